// Round 10
// baseline (384.769 us; speedup 1.0000x reference)
//
#include <hip/hip_runtime.h>
#include <hip/hip_bf16.h>

typedef __bf16 bf16_t;
typedef __bf16 bf16x8 __attribute__((ext_vector_type(8)));
typedef __bf16 bf16x4 __attribute__((ext_vector_type(4)));
typedef float  f32x4  __attribute__((ext_vector_type(4)));

#define NB  8
#define NC  256
#define NC8 32
#define NN  4096

#define MFMA16(a, b, c) __builtin_amdgcn_mfma_f32_16x16x32_bf16((a), (b), (c), 0, 0, 0)

// ---------------------------------------------------------------------------
// Kernel 0: fp32 -> bf16 for all three weight matrices in one launch.
// ---------------------------------------------------------------------------
__global__ __launch_bounds__(256) void cvt_all(const float* __restrict__ wq,
                                               const float* __restrict__ wk,
                                               const float* __restrict__ wv,
                                               bf16_t* __restrict__ wqb,
                                               bf16_t* __restrict__ wkb,
                                               bf16_t* __restrict__ wvb) {
    int i = blockIdx.x * 256 + threadIdx.x;   // 0..20479
    const float* src; bf16_t* dst; int off;
    if (i < 2048)      { src = wq; dst = wqb; off = i; }
    else if (i < 4096) { src = wk; dst = wkb; off = i - 2048; }
    else               { src = wv; dst = wvb; off = i - 4096; }
    float4 v = reinterpret_cast<const float4*>(src)[off];
    bf16x4 o;
    o[0] = (bf16_t)v.x; o[1] = (bf16_t)v.y; o[2] = (bf16_t)v.z; o[3] = (bf16_t)v.w;
    reinterpret_cast<bf16x4*>(dst)[off] = o;
}

// ---------------------------------------------------------------------------
// Kernel 1: LDS-free q/k/v projections per (b, n-tile of 64).
// GEMM in x's native layout: A = weight rows (k=c_in contiguous, bf16),
// B = x[c_in][n] via strided scalar fp32 gathers (lanes r: 64B coalesced),
// D[row=c_out][col=n]. h written natively; ft/gt via small bf16x4 stores.
// No LDS, no barriers, no ds_read_u16 storm.
// ---------------------------------------------------------------------------
__global__ __launch_bounds__(256) void proj2(const float* __restrict__ x,
                                             const bf16_t* __restrict__ wqb,
                                             const float* __restrict__ bq,
                                             const bf16_t* __restrict__ wkb,
                                             const float* __restrict__ bk,
                                             const bf16_t* __restrict__ wvb,
                                             const float* __restrict__ bv,
                                             bf16_t* __restrict__ ft,
                                             bf16_t* __restrict__ gt,
                                             bf16_t* __restrict__ h) {
    const int bx = blockIdx.x;          // 512
    const int b  = bx & 7;              // XCD pin (matches attn's pin)
    const int n0 = ((bx >> 3) & 63) * 64;
    const int t  = threadIdx.x;
    const int w    = t >> 6;
    const int lane = t & 63;
    const int q    = lane >> 4;
    const int r    = lane & 15;

    const float* xb = x + (size_t)b * NC * NN + n0;

    f32x4 vacc[4][4];                   // [ct][nt]: c rows 64w+16ct+, n cols 16nt+
#pragma unroll
    for (int ct = 0; ct < 4; ++ct)
#pragma unroll
        for (int nt = 0; nt < 4; ++nt) vacc[ct][nt] = (f32x4){0.f, 0.f, 0.f, 0.f};
    f32x4 qacc[2], kacc[2];             // [ot]: o rows 16ot+, n cols 16w+ (nt=w)
#pragma unroll
    for (int ot = 0; ot < 2; ++ot) {
        qacc[ot] = (f32x4){0.f, 0.f, 0.f, 0.f};
        kacc[ot] = (f32x4){0.f, 0.f, 0.f, 0.f};
    }

    for (int k0 = 0; k0 < NC; k0 += 32) {
        // B-fragments: B[k=8q+j][n=16nt+r] from fp32 x, cvt to bf16
        const float* xk = xb + (size_t)(k0 + 8 * q) * NN + r;
        bf16x8 bfr[4];
#pragma unroll
        for (int nt = 0; nt < 4; ++nt) {
#pragma unroll
            for (int j = 0; j < 8; ++j)
                bfr[nt][j] = (bf16_t)xk[(size_t)j * NN + 16 * nt];
        }
        // v: A = wv rows [64w+16ct, +16)
#pragma unroll
        for (int ct = 0; ct < 4; ++ct) {
            bf16x8 a = *reinterpret_cast<const bf16x8*>(
                wvb + (size_t)(64 * w + 16 * ct + r) * NC + k0 + 8 * q);
#pragma unroll
            for (int nt = 0; nt < 4; ++nt)
                vacc[ct][nt] = MFMA16(a, bfr[nt], vacc[ct][nt]);
        }
        // q/k: A = wq/wk rows [16ot, +16), B = this wave's nt=w fragment
#pragma unroll
        for (int ot = 0; ot < 2; ++ot) {
            bf16x8 aq = *reinterpret_cast<const bf16x8*>(
                wqb + (size_t)(16 * ot + r) * NC + k0 + 8 * q);
            qacc[ot] = MFMA16(aq, bfr[w], qacc[ot]);
            bf16x8 ak = *reinterpret_cast<const bf16x8*>(
                wkb + (size_t)(16 * ot + r) * NC + k0 + 8 * q);
            kacc[ot] = MFMA16(ak, bfr[w], kacc[ot]);
        }
    }

    // ---- epilogue v: h[b][c][n0+16nt+r], c = 64w+16ct+4q+i
#pragma unroll
    for (int ct = 0; ct < 4; ++ct) {
#pragma unroll
        for (int nt = 0; nt < 4; ++nt) {
#pragma unroll
            for (int i = 0; i < 4; ++i) {
                const int c = 64 * w + 16 * ct + 4 * q + i;
                const int n = n0 + 16 * nt + r;
                h[((size_t)b * NC + c) * NN + n] = (bf16_t)(vacc[ct][nt][i] + bv[c]);
            }
        }
    }
    // ---- epilogue q/k: n = n0+16w+r, o = 16ot+4q+i (bf16x4 store, 8B aligned)
#pragma unroll
    for (int ot = 0; ot < 2; ++ot) {
        const int n = n0 + 16 * w + r;
        bf16x4 fq, fk;
#pragma unroll
        for (int i = 0; i < 4; ++i) {
            const int o = 16 * ot + 4 * q + i;
            fq[i] = (bf16_t)(qacc[ot][i] + bq[o]);
            fk[i] = (bf16_t)(kacc[ot][i] + bk[o]);
        }
        *reinterpret_cast<bf16x4*>(ft + ((size_t)b * NN + n) * NC8 + 16 * ot + 4 * q) = fq;
        *reinterpret_cast<bf16x4*>(gt + ((size_t)b * NN + n) * NC8 + 16 * ot + 4 * q) = fk;
    }
}

// ---------------------------------------------------------------------------
// Kernel 2: attention, m-tile 32, BN=128, 4 blocks/CU (the occupancy play).
// acc = 32 AGPRs; S at iter top (s transient); af prefetched across O phase;
// h ping-pong in statically-named regs; P[2][32*128] = 16KB double-buffered.
// ---------------------------------------------------------------------------
#define O_STEP(HU, HL, KC, LOFF)                                               \
    {                                                                          \
        _Pragma("unroll")                                                      \
        for (int ct = 0; ct < 4; ++ct)                                         \
            HL[ct] = *reinterpret_cast<const bf16x8*>(hrow[ct] + (LOFF));      \
        bf16x8 pf[2];                                                          \
        _Pragma("unroll")                                                      \
        for (int mt = 0; mt < 2; ++mt) {                                       \
            const int row = 16 * mt + r;                                       \
            pf[mt] = *reinterpret_cast<const bf16x8*>(                         \
                &Pb[(row << 7) + (((4 * (KC) + q) ^ rq) << 3)]);               \
        }                                                                      \
        _Pragma("unroll")                                                      \
        for (int ct = 0; ct < 4; ++ct)                                         \
            _Pragma("unroll")                                                  \
            for (int mt = 0; mt < 2; ++mt)                                     \
                acc[ct][mt] = MFMA16(HU[ct], pf[mt], acc[ct][mt]);             \
    }

__global__ __launch_bounds__(256, 4) void attn(const bf16_t* __restrict__ ft,
                                               const bf16_t* __restrict__ gt,
                                               const bf16_t* __restrict__ h,
                                               float* __restrict__ out) {
    __shared__ bf16_t P[2 * 32 * 128];   // 16 KB
    __shared__ float  l_lds[32];

    const int bx = blockIdx.x;       // 1024
    const int b  = bx & 7;           // XCD pin: one batch per XCD
    const int m0 = (bx >> 3) * 32;   // 128 m-tiles per batch
    const int tid  = threadIdx.x;
    const int w    = tid >> 6;
    const int lane = tid & 63;
    const int q    = lane >> 4;
    const int r    = lane & 15;
    const int rq   = r & 7;

    if (tid < 32) l_lds[tid] = 0.f;

    bf16x8 qf[2];
#pragma unroll
    for (int mt = 0; mt < 2; ++mt)
        qf[mt] = *reinterpret_cast<const bf16x8*>(
            gt + ((size_t)b * NN + m0 + 16 * mt + r) * NC8 + 8 * q);

    f32x4 acc[4][2];
#pragma unroll
    for (int ct = 0; ct < 4; ++ct)
#pragma unroll
        for (int mt = 0; mt < 2; ++mt) acc[ct][mt] = (f32x4){0.f, 0.f, 0.f, 0.f};
    float lp[2] = {0.f, 0.f};

    const bf16_t* fb = ft + (size_t)b * NN * NC8;
    const bf16_t* hb = h + (size_t)b * NC * NN;
    const f32x4 zero = (f32x4){0.f, 0.f, 0.f, 0.f};

    const bf16_t* hrow[4];
#pragma unroll
    for (int ct = 0; ct < 4; ++ct)
        hrow[ct] = hb + (size_t)(64 * w + 16 * ct + r) * NN + 8 * q;
    // ft rows for S phase: wave w owns n-rows [32w+16t2+r] of each 128-chunk
    const bf16_t* fptr = fb + (size_t)(32 * w + r) * NC8 + 8 * q;

    // ---- prologue: af for chunk 0; h0 for chunk0/kc0
    bf16x8 af0 = *reinterpret_cast<const bf16x8*>(fptr);
    bf16x8 af1 = *reinterpret_cast<const bf16x8*>(fptr + (size_t)16 * NC8);
    bf16x8 h0[4], h1[4];
#pragma unroll
    for (int ct = 0; ct < 4; ++ct)
        h0[ct] = *reinterpret_cast<const bf16x8*>(hrow[ct]);

    for (int ii = 0; ii < 32; ++ii) {
        bf16_t* Pb = &P[(ii & 1) << 12];
        const int nb = ii * 128;

        // ---- S(ii) from prefetched af, then exp + write P
#pragma unroll
        for (int t2 = 0; t2 < 2; ++t2) {
            f32x4 s[2];
            const bf16x8 a = (t2 == 0) ? af0 : af1;
#pragma unroll
            for (int mt = 0; mt < 2; ++mt) s[mt] = MFMA16(a, qf[mt], zero);
#pragma unroll
            for (int mt = 0; mt < 2; ++mt) {
                float e0 = __expf(s[mt][0]);
                float e1 = __expf(s[mt][1]);
                float e2 = __expf(s[mt][2]);
                float e3 = __expf(s[mt][3]);
                lp[mt] += (e0 + e1) + (e2 + e3);
                bf16x4 pv;
                pv[0] = (bf16_t)e0; pv[1] = (bf16_t)e1; pv[2] = (bf16_t)e2; pv[3] = (bf16_t)e3;
                const int row  = 16 * mt + r;                 // m
                const int nblk = 4 * w + 2 * t2 + (q >> 1);   // n block of 8
                *reinterpret_cast<bf16x4*>(
                    &Pb[(row << 7) + ((nblk ^ rq) << 3) + 4 * (q & 1)]) = pv;
            }
        }
        __syncthreads();

        // ---- prefetch af for chunk ii+1 (in flight across whole O phase)
        const int nld = (ii + 1 < 32 ? ii + 1 : 31) * 128;
        af0 = *reinterpret_cast<const bf16x8*>(fptr + (size_t)nld * NC8);
        af1 = *reinterpret_cast<const bf16x8*>(fptr + (size_t)(nld + 16) * NC8);

        // ---- O phase: 4 k-chunks of 32 n, h ping-pong one chunk ahead
        const int nbn = (ii + 1 < 32 ? nb + 128 : nb);
        O_STEP(h0, h1, 0, nb + 32);
        O_STEP(h1, h0, 1, nb + 64);
        O_STEP(h0, h1, 2, nb + 96);
        O_STEP(h1, h0, 3, nbn);
    }

    // ---- reduce l partials
    __syncthreads();
#pragma unroll
    for (int mt = 0; mt < 2; ++mt) {
        float v = lp[mt];
        v += __shfl_xor(v, 16);
        v += __shfl_xor(v, 32);
        if (q == 0) atomicAdd(&l_lds[16 * mt + r], v);
    }
    __syncthreads();

    // ---- epilogue: out[b][c][m] = acc / l[m]
#pragma unroll
    for (int ct = 0; ct < 4; ++ct) {
#pragma unroll
        for (int mt = 0; mt < 2; ++mt) {
            const int m = m0 + 16 * mt + r;
            const float linv = 1.0f / l_lds[16 * mt + r];
#pragma unroll
            for (int i = 0; i < 4; ++i) {
                const int c = 64 * w + 16 * ct + 4 * q + i;
                out[((size_t)b * NC + c) * NN + m] = acc[ct][mt][i] * linv;
            }
        }
    }
}

extern "C" void kernel_launch(void* const* d_in, const int* in_sizes, int n_in,
                              void* d_out, int out_size, void* d_ws, size_t ws_size,
                              hipStream_t stream) {
    const float* x  = (const float*)d_in[0];
    const float* wq = (const float*)d_in[1];
    const float* bq = (const float*)d_in[2];
    const float* wk = (const float*)d_in[3];
    const float* bk = (const float*)d_in[4];
    const float* wv = (const float*)d_in[5];
    const float* bv = (const float*)d_in[6];
    float* out = (float*)d_out;

    bf16_t* ft  = (bf16_t*)d_ws;                     // [B][N][32]
    bf16_t* gt  = ft + (size_t)NB * NN * NC8;        // [B][N][32]
    bf16_t* hb  = gt + (size_t)NB * NN * NC8;        // [B][C][N]
    bf16_t* wqb = hb + (size_t)NB * NC * NN;         // [32][256]
    bf16_t* wkb = wqb + (size_t)NC8 * NC;            // [32][256]
    bf16_t* wvb = wkb + (size_t)NC8 * NC;            // [256][256]

    cvt_all<<<80, 256, 0, stream>>>(wq, wk, wv, wqb, wkb, wvb);
    proj2<<<NB * (NN / 64), 256, 0, stream>>>(x, wqb, bq, wkb, bk, wvb, bv, ft, gt, hb);
    attn<<<NB * (NN / 32), 256, 0, stream>>>(ft, gt, hb, out);
}

// Round 12
// 278.891 us; speedup vs baseline: 1.3796x; 1.3796x over previous
//
#include <hip/hip_runtime.h>
#include <hip/hip_bf16.h>

typedef __bf16 bf16_t;
typedef __bf16 bf16x8 __attribute__((ext_vector_type(8)));
typedef __bf16 bf16x4 __attribute__((ext_vector_type(4)));
typedef float  f32x4  __attribute__((ext_vector_type(4)));

#define NB  8
#define NC  256
#define NC8 32
#define NN  4096

#define MFMA16(a, b, c) __builtin_amdgcn_mfma_f32_16x16x32_bf16((a), (b), (c), 0, 0, 0)

__device__ __forceinline__ bf16x8 cvt8(const float* p) {
    float4 a = *reinterpret_cast<const float4*>(p);
    float4 b = *reinterpret_cast<const float4*>(p + 4);
    bf16x8 o;
    o[0] = (bf16_t)a.x; o[1] = (bf16_t)a.y; o[2] = (bf16_t)a.z; o[3] = (bf16_t)a.w;
    o[4] = (bf16_t)b.x; o[5] = (bf16_t)b.y; o[6] = (bf16_t)b.z; o[7] = (bf16_t)b.w;
    return o;
}

// ---------------------------------------------------------------------------
// Kernel 1: q/k/v projections, LDS-free, weights converted in-register.
// v-GEMM: A = x-fragment (rows=n), B = wv-fragment (cols=c) -> D[n][c]:
// each thread owns 4 consecutive n at fixed c -> vectorized bf16x4 h-stores.
// Wave w owns c in [64w, 64w+64).   (R11 bug: the 64w term was missing.)
// ---------------------------------------------------------------------------
__global__ __launch_bounds__(256) void proj3(const float* __restrict__ x,
                                             const float* __restrict__ wq,
                                             const float* __restrict__ bq,
                                             const float* __restrict__ wk,
                                             const float* __restrict__ bk,
                                             const float* __restrict__ wv,
                                             const float* __restrict__ bv,
                                             bf16_t* __restrict__ ft,
                                             bf16_t* __restrict__ gt,
                                             bf16_t* __restrict__ h) {
    const int bx = blockIdx.x;          // 512
    const int b  = bx & 7;              // XCD pin (matches attn)
    const int n0 = ((bx >> 3) & 63) * 64;
    const int t  = threadIdx.x;
    const int w    = t >> 6;
    const int lane = t & 63;
    const int q    = lane >> 4;
    const int r    = lane & 15;

    const float* xb = x + (size_t)b * NC * NN + n0;

    f32x4 vacc[4][4];                   // [nt][ct]: D rows n=16nt+4q+i, col c=64w+16ct+r
#pragma unroll
    for (int nt = 0; nt < 4; ++nt)
#pragma unroll
        for (int ct = 0; ct < 4; ++ct) vacc[nt][ct] = (f32x4){0.f, 0.f, 0.f, 0.f};
    f32x4 qacc[2], kacc[2];             // D rows o=16ot+4q+i, col n=16w+r
#pragma unroll
    for (int ot = 0; ot < 2; ++ot) {
        qacc[ot] = (f32x4){0.f, 0.f, 0.f, 0.f};
        kacc[ot] = (f32x4){0.f, 0.f, 0.f, 0.f};
    }

    for (int k0 = 0; k0 < NC; k0 += 32) {
        // x fragments: xf[nt]: lane (q,r) holds x[k0+8q+j][n0+16nt+r], j=0..7
        const float* xk = xb + (size_t)(k0 + 8 * q) * NN + r;
        bf16x8 xf[4];
#pragma unroll
        for (int nt = 0; nt < 4; ++nt) {
#pragma unroll
            for (int j = 0; j < 8; ++j)
                xf[nt][j] = (bf16_t)xk[(size_t)j * NN + 16 * nt];
        }
        // v: B = wv[c=64w+16ct+r][k0+8q..+7] (fp32 -> bf16 in-register)
#pragma unroll
        for (int ct = 0; ct < 4; ++ct) {
            bf16x8 bv8 = cvt8(wv + (size_t)(64 * w + 16 * ct + r) * NC + k0 + 8 * q);
#pragma unroll
            for (int nt = 0; nt < 4; ++nt)
                vacc[nt][ct] = MFMA16(xf[nt], bv8, vacc[nt][ct]);
        }
        // q/k: A = w rows [16ot+r], B = this wave's xf[w]
#pragma unroll
        for (int ot = 0; ot < 2; ++ot) {
            bf16x8 aq = cvt8(wq + (size_t)(16 * ot + r) * NC + k0 + 8 * q);
            qacc[ot] = MFMA16(aq, xf[w], qacc[ot]);
            bf16x8 ak = cvt8(wk + (size_t)(16 * ot + r) * NC + k0 + 8 * q);
            kacc[ot] = MFMA16(ak, xf[w], kacc[ot]);
        }
    }

    // ---- epilogue v: h[b][64w+16ct+r][n0+16nt+4q+i] <- bf16x4 (8B, coalesced)
#pragma unroll
    for (int ct = 0; ct < 4; ++ct) {
        const int c = 64 * w + 16 * ct + r;
        const float bvc = bv[c];
#pragma unroll
        for (int nt = 0; nt < 4; ++nt) {
            bf16x4 hv;
#pragma unroll
            for (int i = 0; i < 4; ++i) hv[i] = (bf16_t)(vacc[nt][ct][i] + bvc);
            *reinterpret_cast<bf16x4*>(
                h + ((size_t)b * NC + c) * NN + n0 + 16 * nt + 4 * q) = hv;
        }
    }
    // ---- epilogue q/k: ft/gt[b][n0+16w+r][16ot+4q+i] <- bf16x4
#pragma unroll
    for (int ot = 0; ot < 2; ++ot) {
        const int n = n0 + 16 * w + r;
        bf16x4 fq, fk;
#pragma unroll
        for (int i = 0; i < 4; ++i) {
            const int o = 16 * ot + 4 * q + i;
            fq[i] = (bf16_t)(qacc[ot][i] + bq[o]);
            fk[i] = (bf16_t)(kacc[ot][i] + bk[o]);
        }
        *reinterpret_cast<bf16x4*>(ft + ((size_t)b * NN + n) * NC8 + 16 * ot + 4 * q) = fq;
        *reinterpret_cast<bf16x4*>(gt + ((size_t)b * NN + n) * NC8 + 16 * ot + 4 * q) = fk;
    }
}

// ---------------------------------------------------------------------------
// Kernel 2: attention — R9 version verbatim (best known: 143 us).
// ---------------------------------------------------------------------------
#define O_STEP(HU, HL, KC, LOFF)                                               \
    {                                                                          \
        _Pragma("unroll")                                                      \
        for (int ct = 0; ct < 4; ++ct)                                         \
            HL[ct] = *reinterpret_cast<const bf16x8*>(hrow[ct] + (LOFF));      \
        bf16x8 pf[4];                                                          \
        _Pragma("unroll")                                                      \
        for (int mt = 0; mt < 4; ++mt) {                                       \
            const int row = 16 * mt + r;                                       \
            pf[mt] = *reinterpret_cast<const bf16x8*>(                         \
                &Pb[(row << 7) + (((4 * (KC) + q) ^ (r & 7)) << 3)]);          \
        }                                                                      \
        _Pragma("unroll")                                                      \
        for (int ct = 0; ct < 4; ++ct)                                         \
            _Pragma("unroll")                                                  \
            for (int mt = 0; mt < 4; ++mt)                                     \
                acc[ct][mt] = MFMA16(HU[ct], pf[mt], acc[ct][mt]);             \
    }

__global__ __launch_bounds__(256, 2) void attn(const bf16_t* __restrict__ ft,
                                               const bf16_t* __restrict__ gt,
                                               const bf16_t* __restrict__ h,
                                               float* __restrict__ out) {
    __shared__ bf16_t P[2 * 64 * 128];   // 32 KB
    __shared__ float  l_lds[64];

    const int bx = blockIdx.x;       // 512
    const int b  = bx & 7;           // XCD pin
    const int m0 = (bx >> 3) * 64;
    const int tid  = threadIdx.x;
    const int w    = tid >> 6;
    const int lane = tid & 63;
    const int q    = lane >> 4;
    const int r    = lane & 15;

    if (tid < 64) l_lds[tid] = 0.f;

    bf16x8 qf[4];
#pragma unroll
    for (int mt = 0; mt < 4; ++mt)
        qf[mt] = *reinterpret_cast<const bf16x8*>(
            gt + ((size_t)b * NN + m0 + 16 * mt + r) * NC8 + 8 * q);

    f32x4 acc[4][4];
#pragma unroll
    for (int ct = 0; ct < 4; ++ct)
#pragma unroll
        for (int mt = 0; mt < 4; ++mt) acc[ct][mt] = (f32x4){0.f, 0.f, 0.f, 0.f};
    float lp[4] = {0.f, 0.f, 0.f, 0.f};

    const bf16_t* fb = ft + (size_t)b * NN * NC8;
    const bf16_t* hb = h + (size_t)b * NC * NN;
    const f32x4 zero = (f32x4){0.f, 0.f, 0.f, 0.f};

    const bf16_t* hrow[4];
#pragma unroll
    for (int ct = 0; ct < 4; ++ct)
        hrow[ct] = hb + (size_t)(64 * w + 16 * ct + r) * NN + 8 * q;
    const bf16_t* fptr = fb + (size_t)(32 * w + r) * NC8 + 8 * q;

    // ---- prologue: s(chunk 0); h0 = chunk0/kc0
    f32x4 s[2][4];
#pragma unroll
    for (int t2 = 0; t2 < 2; ++t2) {
        bf16x8 a0 = *reinterpret_cast<const bf16x8*>(fptr + (size_t)(16 * t2) * NC8);
#pragma unroll
        for (int mt = 0; mt < 4; ++mt) s[t2][mt] = MFMA16(a0, qf[mt], zero);
    }
    bf16x8 h0[4], h1[4];
#pragma unroll
    for (int ct = 0; ct < 4; ++ct)
        h0[ct] = *reinterpret_cast<const bf16x8*>(hrow[ct]);

    const int rq = r & 7;

    for (int ii = 0; ii < 32; ++ii) {
        bf16_t* Pb = &P[(ii & 1) << 13];
        const int nb = ii * 128;

        // ---- exp + write P[cur]
#pragma unroll
        for (int t2 = 0; t2 < 2; ++t2) {
#pragma unroll
            for (int mt = 0; mt < 4; ++mt) {
                float e0 = __expf(s[t2][mt][0]);
                float e1 = __expf(s[t2][mt][1]);
                float e2 = __expf(s[t2][mt][2]);
                float e3 = __expf(s[t2][mt][3]);
                lp[mt] += (e0 + e1) + (e2 + e3);
                bf16x4 pv;
                pv[0] = (bf16_t)e0; pv[1] = (bf16_t)e1; pv[2] = (bf16_t)e2; pv[3] = (bf16_t)e3;
                const int row  = 16 * mt + r;
                const int nblk = 4 * w + 2 * t2 + (q >> 1);
                *reinterpret_cast<bf16x4*>(
                    &Pb[(row << 7) + ((nblk ^ rq) << 3) + 4 * (q & 1)]) = pv;
            }
        }
        __syncthreads();

        // ---- af loads for chunk ii+1 (consumed at iter end)
        const int nld = (ii + 1 < 32 ? ii + 1 : 31) * 128;
        bf16x8 af0 = *reinterpret_cast<const bf16x8*>(fptr + (size_t)nld * NC8);
        bf16x8 af1 = *reinterpret_cast<const bf16x8*>(fptr + (size_t)(nld + 16) * NC8);

        // ---- O phase: 4 k-chunks of 32 n, h ping-pong one chunk ahead
        const int nbn = (ii + 1 < 32 ? nb + 128 : nb);
        O_STEP(h0, h1, 0, nb + 32);
        O_STEP(h1, h0, 1, nb + 64);
        O_STEP(h0, h1, 2, nb + 96);
        O_STEP(h1, h0, 3, nbn);

        // ---- S(ii+1)
#pragma unroll
        for (int mt = 0; mt < 4; ++mt) s[0][mt] = MFMA16(af0, qf[mt], zero);
#pragma unroll
        for (int mt = 0; mt < 4; ++mt) s[1][mt] = MFMA16(af1, qf[mt], zero);
    }

    // ---- reduce l partials
    __syncthreads();
#pragma unroll
    for (int mt = 0; mt < 4; ++mt) {
        float v = lp[mt];
        v += __shfl_xor(v, 16);
        v += __shfl_xor(v, 32);
        if (q == 0) atomicAdd(&l_lds[16 * mt + r], v);
    }
    __syncthreads();

    // ---- epilogue: out[b][c][m] = acc / l[m]
#pragma unroll
    for (int ct = 0; ct < 4; ++ct) {
#pragma unroll
        for (int mt = 0; mt < 4; ++mt) {
            const int m = m0 + 16 * mt + r;
            const float linv = 1.0f / l_lds[16 * mt + r];
#pragma unroll
            for (int i = 0; i < 4; ++i) {
                const int c = 64 * w + 16 * ct + 4 * q + i;
                out[((size_t)b * NC + c) * NN + m] = acc[ct][mt][i] * linv;
            }
        }
    }
}

extern "C" void kernel_launch(void* const* d_in, const int* in_sizes, int n_in,
                              void* d_out, int out_size, void* d_ws, size_t ws_size,
                              hipStream_t stream) {
    const float* x  = (const float*)d_in[0];
    const float* wq = (const float*)d_in[1];
    const float* bq = (const float*)d_in[2];
    const float* wk = (const float*)d_in[3];
    const float* bk = (const float*)d_in[4];
    const float* wv = (const float*)d_in[5];
    const float* bv = (const float*)d_in[6];
    float* out = (float*)d_out;

    bf16_t* ft  = (bf16_t*)d_ws;                     // [B][N][32]
    bf16_t* gt  = ft + (size_t)NB * NN * NC8;        // [B][N][32]
    bf16_t* hb  = gt + (size_t)NB * NN * NC8;        // [B][C][N]

    proj3<<<NB * (NN / 64), 256, 0, stream>>>(x, wq, bq, wk, bk, wv, bv, ft, gt, hb);
    attn<<<NB * (NN / 64), 256, 0, stream>>>(ft, gt, hb, out);
}